// Round 3
// baseline (135.639 us; speedup 1.0000x reference)
//
#include <hip/hip_runtime.h>

#define D 128
#define HDIM 256
#define NB 8            // batch size (fixed by setup_inputs)
#define NSHARD 32       // topk shards per row (256 blocks x 512 thr = 8 waves/CU)
#define CPS 16          // candidates per shard
#define LCPS 4          // per-thread local list (<=4 elems/thread at shard=1563/512)
#define NCAND (NSHARD * CPS)   // 512 candidates per row
#define PHW 16          // phW row stride (floats): [0..7]=ph, [8]=W2
#define WPAD 136        // wL row stride in ushorts (272 B: 16B-aligned, 2-way banks = free)
#define PHT 10          // phT row stride (floats): [0..7]=-ph, [8]=W2, [9]=pad (8B-aligned b64)

typedef short bf16x8 __attribute__((ext_vector_type(8)));
typedef float f32x4 __attribute__((ext_vector_type(4)));
typedef float f32x2 __attribute__((ext_vector_type(2)));

__device__ __forceinline__ unsigned short f2bf(float x) {
    unsigned u = __float_as_uint(x);
    unsigned r = u + 0x7FFF + ((u >> 16) & 1);   // RNE (finite data)
    return (unsigned short)(r >> 16);
}
__device__ __forceinline__ bf16x8 pack_bf8(float4 u, float4 v) {
    union { bf16x8 v8; unsigned short s[8]; } r;
    r.s[0] = f2bf(u.x); r.s[1] = f2bf(u.y); r.s[2] = f2bf(u.z); r.s[3] = f2bf(u.w);
    r.s[4] = f2bf(v.x); r.s[5] = f2bf(v.y); r.s[6] = f2bf(v.z); r.s[7] = f2bf(v.w);
    return r.v8;
}

// CDNA packed-f32 (gfx90a+): D = S0*S1 + S2 per 2-wide element. IEEE fma ->
// bit-identical to the scalar v_fmac path it replaces.
__device__ __forceinline__ f32x2 pk_fma(f32x2 a, f32x2 b, f32x2 c) {
    asm("v_pk_fma_f32 %0, %1, %2, %0" : "+v"(c) : "v"(a), "v"(b));
    return c;
}
__device__ __forceinline__ f32x2 pk_add(f32x2 a, f32x2 b) {
    f32x2 d;
    asm("v_pk_add_f32 %0, %1, %2" : "=v"(d) : "v"(a), "v"(b));
    return d;
}

// key = (ordered_float << 32) | (0xFFFFFFFF - idx): max == (max val, min idx)
__device__ __forceinline__ unsigned long long sk_encode(float v, int idx) {
    unsigned u = __float_as_uint(v);
    u = (u & 0x80000000u) ? ~u : (u | 0x80000000u);
    return ((unsigned long long)u << 32) | (unsigned)(0xFFFFFFFFu - (unsigned)idx);
}
__device__ __forceinline__ float sk_val(unsigned long long key) {
    const unsigned u = (unsigned)(key >> 32);
    return (u & 0x80000000u) ? __uint_as_float(u & 0x7FFFFFFFu) : __uint_as_float(~u);
}
__device__ __forceinline__ int sk_idx(unsigned long long key) {
    return (int)(0xFFFFFFFFu - (unsigned)(key & 0xFFFFFFFFu));
}
__device__ __forceinline__ unsigned long long wave_max64(unsigned long long m) {
#pragma unroll
    for (int s = 32; s > 0; s >>= 1) {
        const unsigned long long o = __shfl_xor(m, s, 64);
        if (o > m) m = o;
    }
    return m;
}

// ---------------------------------------------------------------------------
// K1: prep, 16 blocks x 1024 thr (R1-proven).
// blocks 0..7: ph row b via 4 parallel d-slices + LDS combine.
// blocks 8..15: w1tt = bf16(W1t^T), 16 k-cols each (4 per 256-thr slice).
// ---------------------------------------------------------------------------
__global__ __launch_bounds__(1024) void prep_kernel(
        const int* __restrict__ head, const int* __restrict__ relation,
        const float* __restrict__ ent_emb, const float* __restrict__ rel_emb,
        const float* __restrict__ W1, const float* __restrict__ b1,
        const float* __restrict__ W2, float* __restrict__ phW,
        unsigned short* __restrict__ w1tt) {
    __shared__ float part[4][HDIM];
    const int w = blockIdx.x;
    const int tid = threadIdx.x;
    const int h = tid & 255;
    const int sl = tid >> 8;                       // 0..3 d-slice
    if (w < NB) {
        const int b = w;
        const long hidx = head[b];
        const long ridx = relation[b];
        const float* hrow = ent_emb + hidx * D;
        const float* rrow = rel_emb + ridx * D;
        float acc = 0.f;
        const int d0 = sl * 32;
#pragma unroll 8
        for (int dd = 0; dd < 32; ++dd) {
            const int d = d0 + dd;
            acc += hrow[d] * W1[d * HDIM + h];            // coalesced across h
            acc += rrow[d] * W1[(D + d) * HDIM + h];
        }
        part[sl][h] = acc;
        __syncthreads();
        if (sl == 0) {
            phW[h * PHW + b] = part[0][h] + part[1][h] + part[2][h] + part[3][h] + b1[h];
            if (b == 0) phW[h * PHW + 8] = W2[h];
        }
    } else {
        const int k0 = (w - NB) * 16 + sl * 4;
        const float* w1t = W1 + 2 * D * HDIM;
        unsigned short pk[4];
#pragma unroll
        for (int j = 0; j < 4; ++j)
            pk[j] = f2bf(w1t[(k0 + j) * HDIM + h]);       // coalesced across h
        *(ushort4*)(w1tt + h * D + k0) = make_ushort4(pk[0], pk[1], pk[2], pk[3]);
    }
}

// ---------------------------------------------------------------------------
// K2: MFMA score. R3: the t-loop was LDS-pipe-bound (4xb128 + 9xb32 per
// wave-t ~ 100 DS-cyc; 19.6k cyc/CU ~ 8us > VALU 3.3us > HBM 4.1us). Fix:
// (a) 2 e-tiles/wave (256 thr, 4 waves x 32 e, grid 391 unchanged): bF read
//     once per t feeds BOTH tiles -> B-fragment DS traffic per entity halves;
// (b) phT[h] = {-ph[0..7], w2} stride-10 rows -> nph via 4x ds_read_b64
//     (stride 40B = 16 lanes on 16 banks, conflict-free) instead of 9x b32;
// (c) v_pk_fma_f32 epilogue (pairs over r) + v_pk_add_f32 reduce.
// LDS 79.9 KB -> still 2 blocks/CU. Scores bit-identical (IEEE fma, same
// accumulation order); K3 exact-rescores so K2 is rank-only anyway.
// mfma_f32_16x16x32_bf16: A[m=lane&15][k=(lane>>4)*8+j]; B[k][n=lane&15];
// C: col(n)=lane&15, row(m)=(lane>>4)*4+reg.
// ---------------------------------------------------------------------------
__global__ __launch_bounds__(256, 2) void score_kernel(
        const float* __restrict__ ent_emb, const unsigned short* __restrict__ w1tt,
        const float* __restrict__ phW, float* __restrict__ scores, int E) {
    __shared__ __align__(16) unsigned short wL[HDIM][WPAD];   // 69632 B
    __shared__ __align__(8) float phT[HDIM][PHT];             // 10240 B

    const int tid = threadIdx.x;
    const int lane = tid & 63;
    const int wave = tid >> 6;          // 0..3
    const int lm = lane & 15;
    const int q = lane >> 4;
    const int base_e = blockIdx.x * 128 + wave * 32;

    bf16x8 aF[2][4];
#pragma unroll
    for (int tl = 0; tl < 2; ++tl) {
        const float* arow = ent_emb + (size_t)min(base_e + tl * 16 + lm, E - 1) * D;
#pragma unroll
        for (int kk = 0; kk < 4; ++kk) {
            const float4 u = *(const float4*)(arow + kk * 32 + q * 8);
            const float4 v = *(const float4*)(arow + kk * 32 + q * 8 + 4);
            aF[tl][kk] = pack_bf8(u, v);
        }
    }

#pragma unroll
    for (int i = 0; i < 16; ++i) {
        const int c = i * 256 + tid;           // chunk of 8 ushorts
        const int row = c >> 4;                // 16 chunks per 128-ushort row
        const int col = (c & 15) << 3;
        *(uint4*)(&wL[row][col]) = *(const uint4*)(w1tt + row * D + col);
    }
    {   // all 256 threads: h = tid
        const float4 p0 = *(const float4*)(phW + tid * PHW);
        const float4 p1 = *(const float4*)(phW + tid * PHW + 4);
        phT[tid][0] = -p0.x; phT[tid][1] = -p0.y; phT[tid][2] = -p0.z; phT[tid][3] = -p0.w;
        phT[tid][4] = -p1.x; phT[tid][5] = -p1.y; phT[tid][6] = -p1.z; phT[tid][7] = -p1.w;
        phT[tid][8] = phW[tid * PHW + 8];
    }
    __syncthreads();   // the ONLY barrier

    f32x2 sp[2][16];                           // [tile][b*2+rp]
#pragma unroll
    for (int tl = 0; tl < 2; ++tl)
#pragma unroll
        for (int i = 0; i < 16; ++i) sp[tl][i] = (f32x2){0.f, 0.f};

#pragma unroll
    for (int t = 0; t < 16; ++t) {
        const int h = t * 16 + lm;             // lane's B-row & C-col
        bf16x8 bF[4];
#pragma unroll
        for (int kk = 0; kk < 4; ++kk)
            bF[kk] = *(const bf16x8*)(&wL[h][kk * 32 + q * 8]);   // 2-way banks: free

        const float* ph = phT[h];
        const f32x2 n01 = *(const f32x2*)(ph + 0);   // 4x ds_read_b64, no conflict
        const f32x2 n23 = *(const f32x2*)(ph + 2);
        const f32x2 n45 = *(const f32x2*)(ph + 4);
        const f32x2 n67 = *(const f32x2*)(ph + 6);
        const float w2v = ph[8];
        const f32x2 w2x2 = {w2v, w2v};
        const float nph[8] = {n01.x, n01.y, n23.x, n23.y, n45.x, n45.y, n67.x, n67.y};

#pragma unroll
        for (int tl = 0; tl < 2; ++tl) {
            f32x4 acc = (f32x4){0.f, 0.f, 0.f, 0.f};
#pragma unroll
            for (int kk = 0; kk < 4; ++kk)
                acc = __builtin_amdgcn_mfma_f32_16x16x32_bf16(aF[tl][kk], bF[kk], acc, 0, 0, 0);

#pragma unroll
            for (int b = 0; b < NB; ++b) {
                const float nb = nph[b];
                const f32x2 m0 = {fmaxf(acc[0], nb), fmaxf(acc[1], nb)};
                sp[tl][b * 2 + 0] = pk_fma(m0, w2x2, sp[tl][b * 2 + 0]);
                const f32x2 m1 = {fmaxf(acc[2], nb), fmaxf(acc[3], nb)};
                sp[tl][b * 2 + 1] = pk_fma(m1, w2x2, sp[tl][b * 2 + 1]);
            }
        }
    }

#pragma unroll
    for (int m = 1; m <= 8; m <<= 1) {
#pragma unroll
        for (int tl = 0; tl < 2; ++tl)
#pragma unroll
            for (int i = 0; i < 16; ++i) {
                union { f32x2 f; unsigned long long u; } cv;
                cv.f = sp[tl][i];
                cv.u = __shfl_xor(cv.u, m, 64);
                sp[tl][i] = pk_add(sp[tl][i], cv.f);
            }
    }
    if (lm == 0) {
#pragma unroll
        for (int tl = 0; tl < 2; ++tl)
#pragma unroll
            for (int rp = 0; rp < 2; ++rp)
#pragma unroll
                for (int j = 0; j < 2; ++j) {
                    const int e = base_e + tl * 16 + q * 4 + rp * 2 + j;
                    if (e < E) {
#pragma unroll
                        for (int b = 0; b < NB; ++b)
                            scores[(size_t)b * E + e] = sp[tl][b * 2 + rp][j];
                    }
                }
    }
}

// ---------------------------------------------------------------------------
// K3: shard top-16 + exact fp32 rescore. R2-proven: 256 blocks x 512 thr,
// NSHARD=32. Selection: 8-wave phase-1 -> 128 cands; two parallel bitonic-64
// (waves 0,1) -> 2x16; one 5-stage bitonic merge -> top-16. Rescore: waves
// 0-3 own cands 0-7, waves 4-7 own cands 8-15; reduction order bit-identical.
// No device-scope fences/atomics (R8 lesson).
// ---------------------------------------------------------------------------
__global__ __launch_bounds__(512) void topk_rescore_kernel(
        const float* __restrict__ scores, int E,
        const float* __restrict__ ent_emb, const float* __restrict__ W1,
        const float* __restrict__ phW, const float* __restrict__ b2,
        unsigned long long* __restrict__ cand_exact) {
    const int b = blockIdx.x >> 5;
    const int s = blockIdx.x & 31;
    const int tid = threadIdx.x;
    const int lane = tid & 63;
    const int wave = tid >> 6;                     // 0..7

    __shared__ unsigned long long cl[8 * CPS];     // 128 wave candidates
    __shared__ unsigned long long s2[32];          // two sorted top-16 runs
    __shared__ unsigned long long candk[CPS];
    __shared__ int eIdxs[CPS];
    __shared__ float entR[CPS][D];                 // 8 KB
    __shared__ float red[8][8];

    {
        const int shard = (E + NSHARD - 1) / NSHARD;   // 1563
        const int start = s * shard;
        const int end = min(E, start + shard);
        const float* row = scores + (size_t)b * E;

        unsigned long long keys[LCPS];
#pragma unroll
        for (int i = 0; i < LCPS; ++i) keys[i] = 0ull;

        for (int e = start + tid; e < end; e += 512) {   // <=4 elems/thread: complete
            unsigned long long key = sk_encode(row[e], e);
            if (key > keys[LCPS - 1]) {
#pragma unroll
                for (int j = 0; j < LCPS; ++j) {
                    const bool gt = key > keys[j];
                    const unsigned long long mx = gt ? key : keys[j];
                    key = gt ? keys[j] : key;
                    keys[j] = mx;
                }
            }
        }
        // phase 1: per-wave top-16 by iterative extraction (8 waves parallel)
        for (int r = 0; r < CPS; ++r) {
            const unsigned long long m = wave_max64(keys[0]);
            if (keys[0] == m) {
#pragma unroll
                for (int j = 0; j < LCPS - 1; ++j) keys[j] = keys[j + 1];
                keys[LCPS - 1] = 0ull;
            }
            if (lane == 0) cl[wave * CPS + r] = m;
        }
        __syncthreads();
        // phase 2a: waves 0,1 each bitonic-64-sort one half descending.
        // keys are unique (idx encoded) so ties are impossible.
        if (wave < 2) {
            unsigned long long v = cl[wave * 64 + lane];
#pragma unroll
            for (int kk = 2; kk <= 64; kk <<= 1) {
#pragma unroll
                for (int j = kk >> 1; j > 0; j >>= 1) {
                    const unsigned long long o = __shfl_xor(v, j, 64);
                    const bool keep_min = (((lane & j) == 0) == ((lane & kk) != 0));
                    const unsigned long long mn = v < o ? v : o;
                    const unsigned long long mx = v < o ? o : v;
                    v = keep_min ? mn : mx;
                }
            }
            if (lane < 16) s2[wave * 16 + lane] = v;
        }
        __syncthreads();
        // phase 2b: wave 0 merges the two sorted-16 runs (desc + reversed-asc
        // = bitonic) with a 5-stage descending bitonic merge on lanes 0..31.
        if (wave == 0) {
            unsigned long long v = 0ull;
            if (lane < 16) v = s2[lane];                 // descending run
            else if (lane < 32) v = s2[47 - lane];       // ascending run
#pragma unroll
            for (int j = 16; j > 0; j >>= 1) {           // lanes<32 stay <32
                const unsigned long long o = __shfl_xor(v, j, 64);
                const unsigned long long mn = v < o ? v : o;
                const unsigned long long mx = v < o ? o : v;
                v = ((lane & j) == 0) ? mx : mn;
            }
            if (lane < 16) candk[lane] = v;
        }
        __syncthreads();
    }

    if (tid < CPS) eIdxs[tid] = sk_idx(candk[tid]);
    __syncthreads();
    for (int t = tid; t < CPS * (D / 4); t += 512) {     // exactly 1 iter/thread
        const int rowc = t >> 5, c4 = (t & 31) * 4;
        *(float4*)(&entR[rowc][c4]) =
            *(const float4*)(ent_emb + (size_t)eIdxs[rowc] * D + c4);
    }
    __syncthreads();

    const int h = tid & 255;                       // thread owns h
    const int chalf = tid >> 8;                    // 0: cands 0-7, 1: cands 8-15
    const float* w1t = W1 + 2 * D * HDIM;
    float acc[8];
#pragma unroll
    for (int c = 0; c < 8; ++c) acc[c] = 0.f;
    for (int d0 = 0; d0 < D; d0 += 4) {
        float w[4];
#pragma unroll
        for (int j = 0; j < 4; ++j) w[j] = w1t[(d0 + j) * HDIM + h];    // coalesced
#pragma unroll
        for (int c = 0; c < 8; ++c) {
            const float4 f = *(const float4*)(&entR[chalf * 8 + c][d0]); // broadcast
            acc[c] += f.x * w[0] + f.y * w[1] + f.z * w[2] + f.w * w[3];
        }
    }
    const float phv = phW[h * PHW + b];
    const float w2v = phW[h * PHW + 8];
    float sc[8];
#pragma unroll
    for (int c = 0; c < 8; ++c) sc[c] = fmaxf(acc[c] + phv, 0.f) * w2v;

#pragma unroll
    for (int m = 1; m <= 32; m <<= 1)
#pragma unroll
        for (int c = 0; c < 8; ++c) sc[c] += __shfl_xor(sc[c], m, 64);
    if (lane == 0)
#pragma unroll
        for (int c = 0; c < 8; ++c) red[wave][c] = sc[c];   // wave w: h=(w*64..+63)&255
    __syncthreads();
    if (tid < CPS) {
        const int ch = tid >> 3, ci = tid & 7;     // waves ch*4..ch*4+3, in order
        const float v = red[ch * 4 + 0][ci] + red[ch * 4 + 1][ci] +
                        red[ch * 4 + 2][ci] + red[ch * 4 + 3][ci] + b2[0];
        cand_exact[(size_t)(b * NSHARD + s) * CPS + tid] = sk_encode(v, eIdxs[tid]);
    }
}

// ---------------------------------------------------------------------------
// K4: final top-k per row from 512 exactly-scored keys. 8 blocks x 1 wave
// (row-parallel). Static-index full sort (28 comparators) + k extractions.
// ---------------------------------------------------------------------------
__global__ __launch_bounds__(64) void final_kernel(
        const unsigned long long* __restrict__ cand_exact, int k,
        float* __restrict__ out) {
    const int lane = threadIdx.x;
    const int b = blockIdx.x;
    unsigned long long lk[8];
#pragma unroll
    for (int j = 0; j < 8; ++j)
        lk[j] = cand_exact[(size_t)b * NCAND + j * 64 + lane];   // coalesced
    // full sort descending (static-index exchange sort)
#pragma unroll
    for (int i = 0; i < 7; ++i)
#pragma unroll
        for (int j = i + 1; j < 8; ++j)
            if (lk[i] < lk[j]) {
                const unsigned long long t = lk[i];
                lk[i] = lk[j];
                lk[j] = t;
            }
    for (int r = 0; r < k; ++r) {
        const unsigned long long m = wave_max64(lk[0]);
        if (lk[0] == m) {                      // unique keys -> one owner
#pragma unroll
            for (int j = 0; j < 7; ++j) lk[j] = lk[j + 1];
            lk[7] = 0ull;
        }
        if (lane == 0) {
            out[b * k + r] = (float)sk_idx(m);            // indices
            out[NB * k + b * k + r] = sk_val(m);          // scores
        }
    }
}

// ---------------------------------------------------------------------------
extern "C" void kernel_launch(void* const* d_in, const int* in_sizes, int n_in,
                              void* d_out, int out_size, void* d_ws, size_t ws_size,
                              hipStream_t stream) {
    const int*   head     = (const int*)d_in[0];
    const int*   relation = (const int*)d_in[1];
    const float* ent_emb  = (const float*)d_in[3];
    const float* rel_emb  = (const float*)d_in[4];
    const float* W1       = (const float*)d_in[5];
    const float* b1       = (const float*)d_in[6];
    const float* W2       = (const float*)d_in[7];
    const float* b2       = (const float*)d_in[8];

    const int B = in_sizes[0];          // 8
    const int E = in_sizes[3] / D;      // 50000
    int k = out_size / (2 * B);         // 10
    if (k > CPS) k = CPS;

    char* ws = (char*)d_ws;
    unsigned long long* cand_exact = (unsigned long long*)ws;       //  32 KB
    float*          phW       = (float*)(ws + 32768);               //  16 KB
    unsigned short* w1tt      = (unsigned short*)(ws + 49152);      //  64 KB
    float*          scores    = (float*)(ws + 114688);              // 1.6 MB
    float*          out       = (float*)d_out;

    prep_kernel<<<NB + 8, 1024, 0, stream>>>(head, relation, ent_emb, rel_emb,
                                             W1, b1, W2, phW, w1tt);
    const int nblk = (E + 127) / 128;
    score_kernel<<<nblk, 256, 0, stream>>>(ent_emb, w1tt, phW, scores, E);
    topk_rescore_kernel<<<NB * NSHARD, 512, 0, stream>>>(
        scores, E, ent_emb, W1, phW, b2, cand_exact);
    final_kernel<<<NB, 64, 0, stream>>>(cand_exact, k, out);
}

// Round 4
// 132.097 us; speedup vs baseline: 1.0268x; 1.0268x over previous
//
#include <hip/hip_runtime.h>

#define D 128
#define HDIM 256
#define NB 8            // batch size (fixed by setup_inputs)
#define NSHARD 32       // topk shards per row (256 blocks x 512 thr = 8 waves/CU)
#define CPS 16          // candidates per shard
#define LCPS 4          // per-thread local list (<=4 elems/thread at shard=1563/512)
#define NCAND (NSHARD * CPS)   // 512 candidates per row
#define PHW 16          // phW row stride (floats): [0..7]=ph, [8]=W2
#define WPAD 136        // wL row stride in ushorts (272 B: 16B-aligned, 2-way banks = free)
#define PHT 10          // phT row stride (floats): [0..7]=-ph, [8]=W2, [9]=pad (8B-aligned b64)

typedef short bf16x8 __attribute__((ext_vector_type(8)));
typedef float f32x4 __attribute__((ext_vector_type(4)));
typedef float f32x2 __attribute__((ext_vector_type(2)));

__device__ __forceinline__ unsigned short f2bf(float x) {
    unsigned u = __float_as_uint(x);
    unsigned r = u + 0x7FFF + ((u >> 16) & 1);   // RNE (finite data)
    return (unsigned short)(r >> 16);
}
__device__ __forceinline__ bf16x8 pack_bf8(float4 u, float4 v) {
    union { bf16x8 v8; unsigned short s[8]; } r;
    r.s[0] = f2bf(u.x); r.s[1] = f2bf(u.y); r.s[2] = f2bf(u.z); r.s[3] = f2bf(u.w);
    r.s[4] = f2bf(v.x); r.s[5] = f2bf(v.y); r.s[6] = f2bf(v.z); r.s[7] = f2bf(v.w);
    return r.v8;
}

// CDNA packed-f32 (gfx90a+): D = S0*S1 + S2 per 2-wide element. IEEE fma ->
// bit-identical to the scalar v_fmac path it replaces.
__device__ __forceinline__ f32x2 pk_fma(f32x2 a, f32x2 b, f32x2 c) {
    asm("v_pk_fma_f32 %0, %1, %2, %0" : "+v"(c) : "v"(a), "v"(b));
    return c;
}
__device__ __forceinline__ f32x2 pk_add(f32x2 a, f32x2 b) {
    f32x2 d;
    asm("v_pk_add_f32 %0, %1, %2" : "=v"(d) : "v"(a), "v"(b));
    return d;
}

// key = (ordered_float << 32) | (0xFFFFFFFF - idx): max == (max val, min idx)
__device__ __forceinline__ unsigned long long sk_encode(float v, int idx) {
    unsigned u = __float_as_uint(v);
    u = (u & 0x80000000u) ? ~u : (u | 0x80000000u);
    return ((unsigned long long)u << 32) | (unsigned)(0xFFFFFFFFu - (unsigned)idx);
}
__device__ __forceinline__ float sk_val(unsigned long long key) {
    const unsigned u = (unsigned)(key >> 32);
    return (u & 0x80000000u) ? __uint_as_float(u & 0x7FFFFFFFu) : __uint_as_float(~u);
}
__device__ __forceinline__ int sk_idx(unsigned long long key) {
    return (int)(0xFFFFFFFFu - (unsigned)(key & 0xFFFFFFFFu));
}
__device__ __forceinline__ unsigned long long wave_max64(unsigned long long m) {
#pragma unroll
    for (int s = 32; s > 0; s >>= 1) {
        const unsigned long long o = __shfl_xor(m, s, 64);
        if (o > m) m = o;
    }
    return m;
}

// ---------------------------------------------------------------------------
// K1: prep, 16 blocks x 1024 thr (R1-proven).
// blocks 0..7: ph row b via 4 parallel d-slices + LDS combine.
// blocks 8..15: w1tt = bf16(W1t^T), 16 k-cols each (4 per 256-thr slice).
// ---------------------------------------------------------------------------
__global__ __launch_bounds__(1024) void prep_kernel(
        const int* __restrict__ head, const int* __restrict__ relation,
        const float* __restrict__ ent_emb, const float* __restrict__ rel_emb,
        const float* __restrict__ W1, const float* __restrict__ b1,
        const float* __restrict__ W2, float* __restrict__ phW,
        unsigned short* __restrict__ w1tt) {
    __shared__ float part[4][HDIM];
    const int w = blockIdx.x;
    const int tid = threadIdx.x;
    const int h = tid & 255;
    const int sl = tid >> 8;                       // 0..3 d-slice
    if (w < NB) {
        const int b = w;
        const long hidx = head[b];
        const long ridx = relation[b];
        const float* hrow = ent_emb + hidx * D;
        const float* rrow = rel_emb + ridx * D;
        float acc = 0.f;
        const int d0 = sl * 32;
#pragma unroll 8
        for (int dd = 0; dd < 32; ++dd) {
            const int d = d0 + dd;
            acc += hrow[d] * W1[d * HDIM + h];            // coalesced across h
            acc += rrow[d] * W1[(D + d) * HDIM + h];
        }
        part[sl][h] = acc;
        __syncthreads();
        if (sl == 0) {
            phW[h * PHW + b] = part[0][h] + part[1][h] + part[2][h] + part[3][h] + b1[h];
            if (b == 0) phW[h * PHW + 8] = W2[h];
        }
    } else {
        const int k0 = (w - NB) * 16 + sl * 4;
        const float* w1t = W1 + 2 * D * HDIM;
        unsigned short pk[4];
#pragma unroll
        for (int j = 0; j < 4; ++j)
            pk[j] = f2bf(w1t[(k0 + j) * HDIM + h]);       // coalesced across h
        *(ushort4*)(w1tt + h * D + k0) = make_ushort4(pk[0], pk[1], pk[2], pk[3]);
    }
}

// ---------------------------------------------------------------------------
// K2: MFMA score. R4: back to the R2-proven 512-thr / 1-tile-per-wave /
// 16-waves-per-CU shape (R3's 2-tile 256-thr halved occupancy to 8 waves/CU
// and REGRESSED +2.5us -> the t-loop is latency-bound, waves matter most).
// Kept from R3 (occupancy-neutral, strictly less work per t):
// (a) phT[h] = {-ph[0..7], w2} stride-10 rows -> nph via 4x ds_read_b64 + 1 b32
//     (9 DS ops/t vs 13; stride 40B = conflict-free);
// (b) v_pk_fma_f32 epilogue (64 VALU/t vs 96) + v_pk_add_f32 reduce.
// LDS 79.9 KB -> 2 blocks/CU. nph trick (R2): scores are rank-only (K3
// exact-rescores), so sp += max(acc,-ph)*w2 drops the per-row constant.
// mfma_f32_16x16x32_bf16: A[m=lane&15][k=(lane>>4)*8+j]; B[k][n=lane&15];
// C: col(n)=lane&15, row(m)=(lane>>4)*4+reg.
// ---------------------------------------------------------------------------
__global__ __launch_bounds__(512, 2) void score_kernel(
        const float* __restrict__ ent_emb, const unsigned short* __restrict__ w1tt,
        const float* __restrict__ phW, float* __restrict__ scores, int E) {
    __shared__ __align__(16) unsigned short wL[HDIM][WPAD];   // 69632 B
    __shared__ __align__(8) float phT[HDIM][PHT];             // 10240 B

    const int tid = threadIdx.x;
    const int lane = tid & 63;
    const int wave = tid >> 6;          // 0..7
    const int lm = lane & 15;
    const int q = lane >> 4;
    const int base_e = blockIdx.x * 128 + wave * 16;

    const float* arow = ent_emb + (size_t)min(base_e + lm, E - 1) * D;
    bf16x8 aF[4];
#pragma unroll
    for (int kk = 0; kk < 4; ++kk) {
        const float4 u = *(const float4*)(arow + kk * 32 + q * 8);
        const float4 v = *(const float4*)(arow + kk * 32 + q * 8 + 4);
        aF[kk] = pack_bf8(u, v);
    }

#pragma unroll
    for (int i = 0; i < 8; ++i) {
        const int c = i * 512 + tid;           // chunk of 8 ushorts
        const int row = c >> 4;                // 16 chunks per 128-ushort row
        const int col = (c & 15) << 3;
        *(uint4*)(&wL[row][col]) = *(const uint4*)(w1tt + row * D + col);
    }
    if (tid < HDIM) {
        const float4 p0 = *(const float4*)(phW + tid * PHW);
        const float4 p1 = *(const float4*)(phW + tid * PHW + 4);
        phT[tid][0] = -p0.x; phT[tid][1] = -p0.y; phT[tid][2] = -p0.z; phT[tid][3] = -p0.w;
        phT[tid][4] = -p1.x; phT[tid][5] = -p1.y; phT[tid][6] = -p1.z; phT[tid][7] = -p1.w;
        phT[tid][8] = phW[tid * PHW + 8];
    }
    __syncthreads();   // the ONLY barrier

    f32x2 sp[16];                              // [b*2+rp]
#pragma unroll
    for (int i = 0; i < 16; ++i) sp[i] = (f32x2){0.f, 0.f};

#pragma unroll
    for (int t = 0; t < 16; ++t) {
        const int h = t * 16 + lm;             // lane's B-row & C-col
        bf16x8 bF[4];
#pragma unroll
        for (int kk = 0; kk < 4; ++kk)
            bF[kk] = *(const bf16x8*)(&wL[h][kk * 32 + q * 8]);   // 2-way banks: free

        const float* ph = phT[h];
        const f32x2 n01 = *(const f32x2*)(ph + 0);   // 4x ds_read_b64, no conflict
        const f32x2 n23 = *(const f32x2*)(ph + 2);
        const f32x2 n45 = *(const f32x2*)(ph + 4);
        const f32x2 n67 = *(const f32x2*)(ph + 6);
        const float w2v = ph[8];
        const f32x2 w2x2 = {w2v, w2v};
        const float nph[8] = {n01.x, n01.y, n23.x, n23.y, n45.x, n45.y, n67.x, n67.y};

        f32x4 acc = (f32x4){0.f, 0.f, 0.f, 0.f};
#pragma unroll
        for (int kk = 0; kk < 4; ++kk)
            acc = __builtin_amdgcn_mfma_f32_16x16x32_bf16(aF[kk], bF[kk], acc, 0, 0, 0);

#pragma unroll
        for (int b = 0; b < NB; ++b) {
            const float nb = nph[b];
            const f32x2 m0 = {fmaxf(acc[0], nb), fmaxf(acc[1], nb)};
            sp[b * 2 + 0] = pk_fma(m0, w2x2, sp[b * 2 + 0]);
            const f32x2 m1 = {fmaxf(acc[2], nb), fmaxf(acc[3], nb)};
            sp[b * 2 + 1] = pk_fma(m1, w2x2, sp[b * 2 + 1]);
        }
    }

#pragma unroll
    for (int m = 1; m <= 8; m <<= 1) {
#pragma unroll
        for (int i = 0; i < 16; ++i) {
            union { f32x2 f; unsigned long long u; } cv;
            cv.f = sp[i];
            cv.u = __shfl_xor(cv.u, m, 64);
            sp[i] = pk_add(sp[i], cv.f);
        }
    }
    if (lm == 0) {
#pragma unroll
        for (int rp = 0; rp < 2; ++rp)
#pragma unroll
            for (int j = 0; j < 2; ++j) {
                const int e = base_e + q * 4 + rp * 2 + j;
                if (e < E) {
#pragma unroll
                    for (int b = 0; b < NB; ++b)
                        scores[(size_t)b * E + e] = sp[b * 2 + rp][j];
                }
            }
    }
}

// ---------------------------------------------------------------------------
// K3: shard top-16 + exact fp32 rescore. R2-proven: 256 blocks x 512 thr,
// NSHARD=32. Selection: 8-wave phase-1 -> 128 cands; two parallel bitonic-64
// (waves 0,1) -> 2x16; one 5-stage bitonic merge -> top-16. Rescore: waves
// 0-3 own cands 0-7, waves 4-7 own cands 8-15; reduction order bit-identical.
// No device-scope fences/atomics (R8 lesson).
// ---------------------------------------------------------------------------
__global__ __launch_bounds__(512) void topk_rescore_kernel(
        const float* __restrict__ scores, int E,
        const float* __restrict__ ent_emb, const float* __restrict__ W1,
        const float* __restrict__ phW, const float* __restrict__ b2,
        unsigned long long* __restrict__ cand_exact) {
    const int b = blockIdx.x >> 5;
    const int s = blockIdx.x & 31;
    const int tid = threadIdx.x;
    const int lane = tid & 63;
    const int wave = tid >> 6;                     // 0..7

    __shared__ unsigned long long cl[8 * CPS];     // 128 wave candidates
    __shared__ unsigned long long s2[32];          // two sorted top-16 runs
    __shared__ unsigned long long candk[CPS];
    __shared__ int eIdxs[CPS];
    __shared__ float entR[CPS][D];                 // 8 KB
    __shared__ float red[8][8];

    {
        const int shard = (E + NSHARD - 1) / NSHARD;   // 1563
        const int start = s * shard;
        const int end = min(E, start + shard);
        const float* row = scores + (size_t)b * E;

        unsigned long long keys[LCPS];
#pragma unroll
        for (int i = 0; i < LCPS; ++i) keys[i] = 0ull;

        for (int e = start + tid; e < end; e += 512) {   // <=4 elems/thread: complete
            unsigned long long key = sk_encode(row[e], e);
            if (key > keys[LCPS - 1]) {
#pragma unroll
                for (int j = 0; j < LCPS; ++j) {
                    const bool gt = key > keys[j];
                    const unsigned long long mx = gt ? key : keys[j];
                    key = gt ? keys[j] : key;
                    keys[j] = mx;
                }
            }
        }
        // phase 1: per-wave top-16 by iterative extraction (8 waves parallel)
        for (int r = 0; r < CPS; ++r) {
            const unsigned long long m = wave_max64(keys[0]);
            if (keys[0] == m) {
#pragma unroll
                for (int j = 0; j < LCPS - 1; ++j) keys[j] = keys[j + 1];
                keys[LCPS - 1] = 0ull;
            }
            if (lane == 0) cl[wave * CPS + r] = m;
        }
        __syncthreads();
        // phase 2a: waves 0,1 each bitonic-64-sort one half descending.
        // keys are unique (idx encoded) so ties are impossible.
        if (wave < 2) {
            unsigned long long v = cl[wave * 64 + lane];
#pragma unroll
            for (int kk = 2; kk <= 64; kk <<= 1) {
#pragma unroll
                for (int j = kk >> 1; j > 0; j >>= 1) {
                    const unsigned long long o = __shfl_xor(v, j, 64);
                    const bool keep_min = (((lane & j) == 0) == ((lane & kk) != 0));
                    const unsigned long long mn = v < o ? v : o;
                    const unsigned long long mx = v < o ? o : v;
                    v = keep_min ? mn : mx;
                }
            }
            if (lane < 16) s2[wave * 16 + lane] = v;
        }
        __syncthreads();
        // phase 2b: wave 0 merges the two sorted-16 runs (desc + reversed-asc
        // = bitonic) with a 5-stage descending bitonic merge on lanes 0..31.
        if (wave == 0) {
            unsigned long long v = 0ull;
            if (lane < 16) v = s2[lane];                 // descending run
            else if (lane < 32) v = s2[47 - lane];       // ascending run
#pragma unroll
            for (int j = 16; j > 0; j >>= 1) {           // lanes<32 stay <32
                const unsigned long long o = __shfl_xor(v, j, 64);
                const unsigned long long mn = v < o ? v : o;
                const unsigned long long mx = v < o ? o : v;
                v = ((lane & j) == 0) ? mx : mn;
            }
            if (lane < 16) candk[lane] = v;
        }
        __syncthreads();
    }

    if (tid < CPS) eIdxs[tid] = sk_idx(candk[tid]);
    __syncthreads();
    for (int t = tid; t < CPS * (D / 4); t += 512) {     // exactly 1 iter/thread
        const int rowc = t >> 5, c4 = (t & 31) * 4;
        *(float4*)(&entR[rowc][c4]) =
            *(const float4*)(ent_emb + (size_t)eIdxs[rowc] * D + c4);
    }
    __syncthreads();

    const int h = tid & 255;                       // thread owns h
    const int chalf = tid >> 8;                    // 0: cands 0-7, 1: cands 8-15
    const float* w1t = W1 + 2 * D * HDIM;
    float acc[8];
#pragma unroll
    for (int c = 0; c < 8; ++c) acc[c] = 0.f;
    for (int d0 = 0; d0 < D; d0 += 4) {
        float w[4];
#pragma unroll
        for (int j = 0; j < 4; ++j) w[j] = w1t[(d0 + j) * HDIM + h];    // coalesced
#pragma unroll
        for (int c = 0; c < 8; ++c) {
            const float4 f = *(const float4*)(&entR[chalf * 8 + c][d0]); // broadcast
            acc[c] += f.x * w[0] + f.y * w[1] + f.z * w[2] + f.w * w[3];
        }
    }
    const float phv = phW[h * PHW + b];
    const float w2v = phW[h * PHW + 8];
    float sc[8];
#pragma unroll
    for (int c = 0; c < 8; ++c) sc[c] = fmaxf(acc[c] + phv, 0.f) * w2v;

#pragma unroll
    for (int m = 1; m <= 32; m <<= 1)
#pragma unroll
        for (int c = 0; c < 8; ++c) sc[c] += __shfl_xor(sc[c], m, 64);
    if (lane == 0)
#pragma unroll
        for (int c = 0; c < 8; ++c) red[wave][c] = sc[c];   // wave w: h=(w*64..+63)&255
    __syncthreads();
    if (tid < CPS) {
        const int ch = tid >> 3, ci = tid & 7;     // waves ch*4..ch*4+3, in order
        const float v = red[ch * 4 + 0][ci] + red[ch * 4 + 1][ci] +
                        red[ch * 4 + 2][ci] + red[ch * 4 + 3][ci] + b2[0];
        cand_exact[(size_t)(b * NSHARD + s) * CPS + tid] = sk_encode(v, eIdxs[tid]);
    }
}

// ---------------------------------------------------------------------------
// K4: final top-k per row from 512 exactly-scored keys. 8 blocks x 1 wave
// (row-parallel). Static-index full sort (28 comparators) + k extractions.
// ---------------------------------------------------------------------------
__global__ __launch_bounds__(64) void final_kernel(
        const unsigned long long* __restrict__ cand_exact, int k,
        float* __restrict__ out) {
    const int lane = threadIdx.x;
    const int b = blockIdx.x;
    unsigned long long lk[8];
#pragma unroll
    for (int j = 0; j < 8; ++j)
        lk[j] = cand_exact[(size_t)b * NCAND + j * 64 + lane];   // coalesced
    // full sort descending (static-index exchange sort)
#pragma unroll
    for (int i = 0; i < 7; ++i)
#pragma unroll
        for (int j = i + 1; j < 8; ++j)
            if (lk[i] < lk[j]) {
                const unsigned long long t = lk[i];
                lk[i] = lk[j];
                lk[j] = t;
            }
    for (int r = 0; r < k; ++r) {
        const unsigned long long m = wave_max64(lk[0]);
        if (lk[0] == m) {                      // unique keys -> one owner
#pragma unroll
            for (int j = 0; j < 7; ++j) lk[j] = lk[j + 1];
            lk[7] = 0ull;
        }
        if (lane == 0) {
            out[b * k + r] = (float)sk_idx(m);            // indices
            out[NB * k + b * k + r] = sk_val(m);          // scores
        }
    }
}

// ---------------------------------------------------------------------------
extern "C" void kernel_launch(void* const* d_in, const int* in_sizes, int n_in,
                              void* d_out, int out_size, void* d_ws, size_t ws_size,
                              hipStream_t stream) {
    const int*   head     = (const int*)d_in[0];
    const int*   relation = (const int*)d_in[1];
    const float* ent_emb  = (const float*)d_in[3];
    const float* rel_emb  = (const float*)d_in[4];
    const float* W1       = (const float*)d_in[5];
    const float* b1       = (const float*)d_in[6];
    const float* W2       = (const float*)d_in[7];
    const float* b2       = (const float*)d_in[8];

    const int B = in_sizes[0];          // 8
    const int E = in_sizes[3] / D;      // 50000
    int k = out_size / (2 * B);         // 10
    if (k > CPS) k = CPS;

    char* ws = (char*)d_ws;
    unsigned long long* cand_exact = (unsigned long long*)ws;       //  32 KB
    float*          phW       = (float*)(ws + 32768);               //  16 KB
    unsigned short* w1tt      = (unsigned short*)(ws + 49152);      //  64 KB
    float*          scores    = (float*)(ws + 114688);              // 1.6 MB
    float*          out       = (float*)d_out;

    prep_kernel<<<NB + 8, 1024, 0, stream>>>(head, relation, ent_emb, rel_emb,
                                             W1, b1, W2, phW, w1tt);
    const int nblk = (E + 127) / 128;
    score_kernel<<<nblk, 512, 0, stream>>>(ent_emb, w1tt, phW, scores, E);
    topk_rescore_kernel<<<NB * NSHARD, 512, 0, stream>>>(
        scores, E, ent_emb, W1, phW, b2, cand_exact);
    final_kernel<<<NB, 64, 0, stream>>>(cand_exact, k, out);
}